// Round 4
// baseline (498.807 us; speedup 1.0000x reference)
//
#include <hip/hip_runtime.h>
#include <cstddef>
#include <cstdint>

#define B_ 4
#define C_ 256
#define N_ 4096
#define QK_BF 1048576                    /* bf16 elems: qk_t [b][N][64] (q ch 0..31, k ch 32..63) */
#define D_BF  4194304                    /* bf16 elems: [b][256][N] raw y3 -> d                   */
#define D_OFF_B   ((size_t)QK_BF * 2)    /* 2 MB  */
#define SUM_OFF_B (D_OFF_B + (size_t)D_BF * 2)  /* 10 MB: sum[320],sumsq[320],sc[320],bi[320] */
#define ML_OFF_B  (SUM_OFF_B + 1280 * 4)        /* ml[b][n]: 16384 floats */

typedef unsigned short bfraw;
typedef __attribute__((ext_vector_type(8))) short short8;
typedef __attribute__((ext_vector_type(4))) float float4v;
typedef __attribute__((ext_vector_type(4))) bfraw bfraw4;

__device__ inline bfraw f2bf(float f) {
    union { float f; uint32_t u; } c; c.f = f;
    uint32_t u = c.u;
    u += 0x7fffu + ((u >> 16) & 1u);     // RNE
    return (bfraw)(u >> 16);
}
__device__ inline float bf2f(bfraw h) {
    union { uint32_t u; float f; } c; c.u = ((uint32_t)h) << 16;
    return c.f;
}

// ---------------------------------------------------------------------------
// Kernel 0: zero the stats accumulators (ws is poisoned 0xAA every launch).
// ---------------------------------------------------------------------------
__global__ void zero_kernel(float* __restrict__ sums) {
    for (int i = threadIdx.x; i < 640; i += 256) sums[i] = 0.f;
}

// ---------------------------------------------------------------------------
// Kernel 1: y = w @ x, all 320 channels, x read ONCE.
// Grid (512 col-tiles of 32, 2 o-splits of 160). Block 256 = 16tx x 16ty,
// thread tile 10o x 2n, fp32.  Fused: per-channel sum/sumsq atomics,
// bf16 stores (qk transposed [b][n][64] via LDS bounce; d [b][c][n]).
// ---------------------------------------------------------------------------
__global__ __launch_bounds__(256) void ygemm_kernel(
    const float* __restrict__ x, const float* __restrict__ w1,
    const float* __restrict__ w2, const float* __restrict__ w3,
    uint8_t* __restrict__ wsb)
{
    __shared__ __align__(16) float Ws[32][164];   // [c][o-local 160]
    __shared__ __align__(16) float Xs[32][36];    // [c][n 32]
    __shared__ bfraw Ts[64][36];                  // qk transpose bounce
    const int colTile = blockIdx.x;               // 0..511
    const int os = blockIdx.y;                    // 0..1
    const int b  = (colTile << 5) / N_;
    const int n0 = (colTile << 5) & (N_ - 1);
    const int obase = os * 160;
    const int tid = threadIdx.x;
    const int tx = tid & 15, ty = tid >> 4;
    const int o0l = ty * 10;
    const int wc  = tid & 31;
    const int wob = tid >> 5;
    const int xn  = tid & 31;
    const int xcb = tid >> 5;
    float acc[10][2] = {};

    for (int cb = 0; cb < 8; ++cb) {
#pragma unroll
        for (int i = 0; i < 20; ++i) {
            int ol = wob + (i << 3);
            int og = obase + ol;
            const float* wr = (og < 32) ? (w1 + og * C_)
                              : (og < 64) ? (w2 + (og - 32) * C_)
                                          : (w3 + (og - 64) * C_);
            Ws[wc][ol] = wr[(cb << 5) + wc];
        }
#pragma unroll
        for (int i = 0; i < 4; ++i) {
            int cl = xcb + (i << 3);
            Xs[cl][xn] = x[((size_t)b * C_ + (cb << 5) + cl) * N_ + n0 + xn];
        }
        __syncthreads();
#pragma unroll 4
        for (int k = 0; k < 32; ++k) {
            float2 xv = *(const float2*)&Xs[k][tx << 1];
            float wv[10];
#pragma unroll
            for (int j = 0; j < 5; ++j) {
                float2 t = *(const float2*)&Ws[k][o0l + (j << 1)];
                wv[2 * j] = t.x; wv[2 * j + 1] = t.y;
            }
#pragma unroll
            for (int i = 0; i < 10; ++i) {
                acc[i][0] = fmaf(wv[i], xv.x, acc[i][0]);
                acc[i][1] = fmaf(wv[i], xv.y, acc[i][1]);
            }
        }
        __syncthreads();
    }
    float* sums  = (float*)(wsb + SUM_OFF_B);
    float* sumsq = sums + 320;
    bfraw* qkt = (bfraw*)wsb;
    bfraw* db  = (bfraw*)(wsb + D_OFF_B);
#pragma unroll
    for (int i = 0; i < 10; ++i) {
        float s  = acc[i][0] + acc[i][1];
        float ss = acc[i][0] * acc[i][0] + acc[i][1] * acc[i][1];
#pragma unroll
        for (int m = 1; m < 16; m <<= 1) {
            s  += __shfl_xor(s, m);
            ss += __shfl_xor(ss, m);
        }
        int og = obase + o0l + i;
        if (tx == 0) {
            atomicAdd(&sums[og], s);
            atomicAdd(&sumsq[og], ss);
        }
        if (og < 64) {
            Ts[og][(tx << 1) + 0] = f2bf(acc[i][0]);
            Ts[og][(tx << 1) + 1] = f2bf(acc[i][1]);
        } else {
            uint32_t pv = (uint32_t)f2bf(acc[i][0]) | ((uint32_t)f2bf(acc[i][1]) << 16);
            *(uint32_t*)&db[((size_t)b * C_ + (og - 64)) * N_ + n0 + (tx << 1)] = pv;
        }
    }
    if (os == 0) {
        __syncthreads();
        int n = tid >> 3, seg = tid & 7;
        short8 v;
#pragma unroll
        for (int j = 0; j < 8; ++j) v[j] = (short)Ts[seg * 8 + j][n];
        *(short8*)&qkt[((size_t)(b * N_ + n0 + n) << 6) + seg * 8] = v;
    }
}

// ---------------------------------------------------------------------------
// Kernel 2: finalize BN -> folded scale/bias per channel.
// ---------------------------------------------------------------------------
__global__ void finalize_kernel(
    const float* __restrict__ g1, const float* __restrict__ b1,
    const float* __restrict__ g2, const float* __restrict__ b2,
    const float* __restrict__ g3, const float* __restrict__ b3,
    float* __restrict__ sums)
{
    int ch = threadIdx.x;
    if (ch >= 320) return;
    const float inv = 1.0f / (float)(B_ * N_);
    float mean = sums[ch] * inv;
    float var = sums[320 + ch] * inv - mean * mean;
    float g, bb;
    if (ch < 32)      { g = g1[ch];      bb = b1[ch]; }
    else if (ch < 64) { g = g2[ch - 32]; bb = b2[ch - 32]; }
    else              { g = g3[ch - 64]; bb = b3[ch - 64]; }
    float sc = g * rsqrtf(var + 1e-5f);
    sums[640 + ch] = sc;
    sums[960 + ch] = bb - sc * mean;
}

// ---------------------------------------------------------------------------
// Kernel 3: in-place bf16 relu(sc*y + bi).
// ---------------------------------------------------------------------------
__global__ __launch_bounds__(256) void affine_kernel(uint8_t* __restrict__ wsb)
{
    bfraw* base = (bfraw*)wsb;
    const float* sc = (const float*)(wsb + SUM_OFF_B) + 640;
    const float* bi = sc + 320;
    size_t i8 = ((size_t)blockIdx.x * 256 + threadIdx.x) * 8;
    bfraw4 v0 = *(bfraw4*)&base[i8];
    bfraw4 v1 = *(bfraw4*)&base[i8 + 4];
    if (i8 < QK_BF) {
        int ch0 = (int)(i8 & 63);
        float4 s0 = *(const float4*)&sc[ch0];
        float4 s1 = *(const float4*)&sc[ch0 + 4];
        float4 c0 = *(const float4*)&bi[ch0];
        float4 c1 = *(const float4*)&bi[ch0 + 4];
        float sa[8] = {s0.x, s0.y, s0.z, s0.w, s1.x, s1.y, s1.z, s1.w};
        float ca[8] = {c0.x, c0.y, c0.z, c0.w, c1.x, c1.y, c1.z, c1.w};
#pragma unroll
        for (int j = 0; j < 4; ++j) {
            v0[j] = f2bf(fmaxf(0.f, fmaf(sa[j],     bf2f(v0[j]), ca[j])));
            v1[j] = f2bf(fmaxf(0.f, fmaf(sa[j + 4], bf2f(v1[j]), ca[j + 4])));
        }
    } else {
        int ch = 64 + (int)(((i8 - QK_BF) >> 12) & 255);
        float s = sc[ch], b = bi[ch];
#pragma unroll
        for (int j = 0; j < 4; ++j) {
            v0[j] = f2bf(fmaxf(0.f, fmaf(s, bf2f(v0[j]), b)));
            v1[j] = f2bf(fmaxf(0.f, fmaf(s, bf2f(v1[j]), b)));
        }
    }
    *(bfraw4*)&base[i8] = v0;
    *(bfraw4*)&base[i8 + 4] = v1;
}

// ---------------------------------------------------------------------------
// Kernel 4: softmax stats pass.  ml[b][q] = rowmax + ln(rowsum of exp).
// Grid 256 (4b x 64 q-groups), 4 waves, wave = one 16-q tile. No LDS/barrier.
// ---------------------------------------------------------------------------
__global__ __launch_bounds__(256) void mlpass_kernel(uint8_t* __restrict__ wsb)
{
    const bfraw* qkt = (const bfraw*)wsb;
    float* ml = (float*)(wsb + ML_OFF_B);
    const int id = blockIdx.x;
    const int b = id & 3;
    const int n0q = (id >> 2) << 6;
    const int tid = threadIdx.x;
    const int w = tid >> 6, l = tid & 63, lq = l & 15, lg = l >> 4;
    const bfraw* qkb = qkt + ((size_t)b * N_ << 6);
    const short8 qfrag = *(const short8*)&qkb[((size_t)(n0q + w * 16 + lq) << 6) + lg * 8];

    float mx = -1e30f, sum = 0.f;
    for (int n0k = 0; n0k < N_; n0k += 128) {
        float4v st[8];
#pragma unroll
        for (int kt = 0; kt < 8; ++kt) {
            short8 kf = *(const short8*)&qkb[((size_t)(n0k + kt * 16 + lq) << 6) + 32 + lg * 8];
            float4v z = {0.f, 0.f, 0.f, 0.f};
            st[kt] = __builtin_amdgcn_mfma_f32_16x16x32_bf16(kf, qfrag, z, 0, 0, 0);
        }
        float m1 = st[0][0];
#pragma unroll
        for (int kt = 0; kt < 8; ++kt)
#pragma unroll
            for (int r = 0; r < 4; ++r) m1 = fmaxf(m1, st[kt][r]);
        float nm = fmaxf(mx, m1);
        float ae = 0.f;
#pragma unroll
        for (int kt = 0; kt < 8; ++kt)
#pragma unroll
            for (int r = 0; r < 4; ++r) ae += __expf(st[kt][r] - nm);
        sum = sum * __expf(mx - nm) + ae;
        mx = nm;
    }
#pragma unroll
    for (int m = 16; m < 64; m <<= 1) {
        float mo = __shfl_xor(mx, m);
        float so = __shfl_xor(sum, m);
        float nm = fmaxf(mx, mo);
        sum = sum * __expf(mx - nm) + so * __expf(mo - nm);
        mx = nm;
    }
    if (lg == 0) ml[b * N_ + n0q + w * 16 + lq] = mx + __logf(sum);
}

// ---------------------------------------------------------------------------
// Kernel 5: PV flash pass (two-pass: ml known => stateless iterations).
// Grid 512: id&3=b, (id>>2)&1=c-half, id>>3=q-group. TK=128, 1 barrier/iter,
// register prefetch of K/D frags across the barrier.  p = exp(s - ml) is
// final (normalized); epilogue: out = x + O.
// ---------------------------------------------------------------------------
__global__ __launch_bounds__(256, 2) void flash_kernel(
    const float* __restrict__ x, const uint8_t* __restrict__ wsb,
    float* __restrict__ out)
{
    const bfraw* qkt = (const bfraw*)wsb;
    const bfraw* db  = (const bfraw*)(wsb + D_OFF_B);
    const float* ml  = (const float*)(wsb + ML_OFF_B);
    __shared__ bfraw Pl[2][64 * 128];    // [q][k] XOR-swizzled 8-elem granules

    const int id  = blockIdx.x;
    const int b   = id & 3;
    const int hf  = (id >> 2) & 1;
    const int n0q = (id >> 3) << 6;
    const int tid = threadIdx.x;
    const int w   = tid >> 6;
    const int l   = tid & 63;
    const int lq  = l & 15;
    const int lg  = l >> 4;
    const int sw  = lq & 7;

    const bfraw* qkb   = qkt + ((size_t)b * N_ << 6);
    const bfraw* dbase = db + ((size_t)b * C_ + hf * 128) * N_;

    const short8 qfrag = *(const short8*)&qkb[((size_t)(n0q + w * 16 + lq) << 6) + lg * 8];
    const float  mlq   = ml[b * N_ + n0q + w * 16 + lq];

    float4v acc[2][4];
#pragma unroll
    for (int i = 0; i < 2; ++i)
#pragma unroll
        for (int j = 0; j < 4; ++j) acc[i][j] = (float4v){0.f, 0.f, 0.f, 0.f};

    // preload iter-0 K and D fragments
    short8 kf[8], df[2][4];
#pragma unroll
    for (int kt = 0; kt < 8; ++kt)
        kf[kt] = *(const short8*)&qkb[((size_t)(kt * 16 + lq) << 6) + 32 + lg * 8];
#pragma unroll
    for (int ct = 0; ct < 2; ++ct) {
        int c = (ct * 4 + w) * 16 + lq;
#pragma unroll
        for (int ch = 0; ch < 4; ++ch)
            df[ct][ch] = *(const short8*)&dbase[(size_t)c * N_ + ch * 32 + lg * 8];
    }

    for (int it = 0; it < 32; ++it) {
        const int ib = it & 1;
        const int nk = ((it + 1) & 31) << 7;   // next-iter base (wraps; harmless)
        // ---- scores for q-tile w ----
        float4v st[8];
#pragma unroll
        for (int kt = 0; kt < 8; ++kt) {
            float4v z = {0.f, 0.f, 0.f, 0.f};
            st[kt] = __builtin_amdgcn_mfma_f32_16x16x32_bf16(kf[kt], qfrag, z, 0, 0, 0);
        }
        // prefetch next K frags (consumed above; long latency window follows)
#pragma unroll
        for (int kt = 0; kt < 8; ++kt)
            kf[kt] = *(const short8*)&qkb[((size_t)(nk + kt * 16 + lq) << 6) + 32 + lg * 8];
        // ---- p = exp(s - ml), pack, swizzled LDS write ----
#pragma unroll
        for (int kt = 0; kt < 8; ++kt) {
            bfraw4 pk;
#pragma unroll
            for (int r = 0; r < 4; ++r) pk[r] = f2bf(__expf(st[kt][r] - mlq));
            int g = (2 * kt + (lg >> 1)) ^ sw;
            *(bfraw4*)&Pl[ib][(w * 16 + lq) * 128 + g * 8 + (lg & 1) * 4] = pk;
        }
        __syncthreads();
        // ---- PV: O^T[c][q] += D * P^T ----
#pragma unroll
        for (int ch = 0; ch < 4; ++ch) {
            short8 bfr[4];
#pragma unroll
            for (int qt = 0; qt < 4; ++qt) {
                int g = (4 * ch + lg) ^ sw;
                bfr[qt] = *(const short8*)&Pl[ib][(qt * 16 + lq) * 128 + g * 8];
            }
#pragma unroll
            for (int ct = 0; ct < 2; ++ct)
#pragma unroll
                for (int qt = 0; qt < 4; ++qt)
                    acc[ct][qt] = __builtin_amdgcn_mfma_f32_16x16x32_bf16(df[ct][ch], bfr[qt], acc[ct][qt], 0, 0, 0);
            // prefetch next D frags for this chunk (just consumed)
#pragma unroll
            for (int ct = 0; ct < 2; ++ct) {
                int c = (ct * 4 + w) * 16 + lq;
                df[ct][ch] = *(const short8*)&dbase[(size_t)c * N_ + nk + ch * 32 + lg * 8];
            }
        }
    }
    // ---- epilogue: out = x + O ----
#pragma unroll
    for (int ct = 0; ct < 2; ++ct)
#pragma unroll
        for (int r = 0; r < 4; ++r) {
            int c = hf * 128 + (ct * 4 + w) * 16 + lg * 4 + r;
            size_t base = ((size_t)b * C_ + c) * N_ + n0q;
#pragma unroll
            for (int qt = 0; qt < 4; ++qt) {
                size_t idx = base + qt * 16 + lq;
                out[idx] = x[idx] + acc[ct][qt][r];
            }
        }
}

extern "C" void kernel_launch(void* const* d_in, const int* in_sizes, int n_in,
                              void* d_out, int out_size, void* d_ws, size_t ws_size,
                              hipStream_t stream) {
    (void)in_sizes; (void)n_in; (void)out_size; (void)ws_size;
    const float* x  = (const float*)d_in[0];
    const float* w1 = (const float*)d_in[1];
    const float* w2 = (const float*)d_in[2];
    const float* w3 = (const float*)d_in[3];
    const float* g1 = (const float*)d_in[4];
    const float* b1 = (const float*)d_in[5];
    const float* g2 = (const float*)d_in[6];
    const float* b2 = (const float*)d_in[7];
    const float* g3 = (const float*)d_in[8];
    const float* b3 = (const float*)d_in[9];
    uint8_t* wsb = (uint8_t*)d_ws;
    float* sums = (float*)(wsb + SUM_OFF_B);
    float* outp = (float*)d_out;

    zero_kernel<<<1, 256, 0, stream>>>(sums);
    ygemm_kernel<<<dim3(512, 2), 256, 0, stream>>>(x, w1, w2, w3, wsb);
    finalize_kernel<<<1, 320, 0, stream>>>(g1, b1, g2, b2, g3, b3, sums);
    affine_kernel<<<(QK_BF + D_BF) / 8 / 256, 256, 0, stream>>>(wsb);
    mlpass_kernel<<<256, 256, 0, stream>>>(wsb);
    flash_kernel<<<N_ / 64 * B_ * 2, 256, 0, stream>>>(x, wsb, outp);
}

// Round 5
// 302.386 us; speedup vs baseline: 1.6496x; 1.6496x over previous
//
#include <hip/hip_runtime.h>
#include <cstddef>
#include <cstdint>

#define B_ 4
#define C_ 256
#define N_ 4096
#define QK_BF 1048576                    /* bf16 elems: qk_t [b][N][64] (q ch 0..31, k ch 32..63) */
#define D_BF  4194304                    /* bf16 elems: [b][256][N] y3 -> d                       */
#define D_OFF_B   ((size_t)QK_BF * 2)    /* 2 MB  */
#define SUM_OFF_B (D_OFF_B + (size_t)D_BF * 2)  /* 10 MB: sum[320],sumsq[320],sc[320],bi[320] */
#define ML_OFF_B  (SUM_OFF_B + 1280 * 4)        /* ml[b][n]: 16384 floats */
#define XH_OFF_B  (ML_OFF_B + 65536)            /* xt hi [b][n][256] bf16: 8 MB */
#define XL_OFF_B  (XH_OFF_B + (size_t)8 * 1024 * 1024)
#define WH_OFF_B  (XL_OFF_B + (size_t)8 * 1024 * 1024)  /* w hi [320][256] bf16 */
#define WL_OFF_B  (WH_OFF_B + 163840)

typedef unsigned short bfraw;
typedef __attribute__((ext_vector_type(8))) short short8;
typedef __attribute__((ext_vector_type(4))) float float4v;
typedef __attribute__((ext_vector_type(4))) bfraw bfraw4;

__device__ inline bfraw f2bf(float f) {
    union { float f; uint32_t u; } c; c.f = f;
    uint32_t u = c.u;
    u += 0x7fffu + ((u >> 16) & 1u);     // RNE
    return (bfraw)(u >> 16);
}
__device__ inline float bf2f(bfraw h) {
    union { uint32_t u; float f; } c; c.u = ((uint32_t)h) << 16;
    return c.f;
}

// ---------------------------------------------------------------------------
// Kernel 0: zero the stats accumulators.
// ---------------------------------------------------------------------------
__global__ void zero_kernel(float* __restrict__ sums) {
    for (int i = threadIdx.x; i < 640; i += 256) sums[i] = 0.f;
}

// ---------------------------------------------------------------------------
// Kernel 1a: split w1|w2|w3 into bf16 hi/lo planes [320][256].
// ---------------------------------------------------------------------------
__global__ __launch_bounds__(256) void wsplit_kernel(
    const float* __restrict__ w1, const float* __restrict__ w2,
    const float* __restrict__ w3, uint8_t* __restrict__ wsb)
{
    bfraw* wh = (bfraw*)(wsb + WH_OFF_B);
    bfraw* wl = (bfraw*)(wsb + WL_OFF_B);
    int idx4 = (blockIdx.x * 256 + threadIdx.x) * 4;   // grid 80 -> 81920
    int ch = idx4 >> 8, k = idx4 & 255;
    const float* wr = (ch < 32) ? (w1 + ch * C_)
                      : (ch < 64) ? (w2 + (ch - 32) * C_)
                                  : (w3 + (ch - 64) * C_);
    float4 v = *(const float4*)&wr[k];
    float va[4] = {v.x, v.y, v.z, v.w};
    bfraw4 h, l;
#pragma unroll
    for (int j = 0; j < 4; ++j) {
        h[j] = f2bf(va[j]);
        l[j] = f2bf(va[j] - bf2f(h[j]));
    }
    *(bfraw4*)&wh[idx4] = h;
    *(bfraw4*)&wl[idx4] = l;
}

// ---------------------------------------------------------------------------
// Kernel 1b: transpose+split x -> xt_hi/xt_lo [b][n][256cin] bf16.
// 64cin x 64n tiles via LDS bounce. Grid 1024 = 4b x 4ctile x 64ntile.
// ---------------------------------------------------------------------------
__global__ __launch_bounds__(256) void xtsplit_kernel(
    const float* __restrict__ x, uint8_t* __restrict__ wsb)
{
    __shared__ float Ls[64][65];
    bfraw* xh = (bfraw*)(wsb + XH_OFF_B);
    bfraw* xl = (bfraw*)(wsb + XL_OFF_B);
    const int id = blockIdx.x;
    const int b  = id >> 8;
    const int c0 = ((id >> 6) & 3) << 6;
    const int n0 = (id & 63) << 6;
    const int t  = threadIdx.x;
    {
        int cl = t >> 4, nc = (t & 15) << 2;
#pragma unroll
        for (int i = 0; i < 4; ++i) {
            float4 v = *(const float4*)&x[((size_t)b * C_ + c0 + cl + i * 16) * N_ + n0 + nc];
            Ls[cl + i * 16][nc + 0] = v.x;
            Ls[cl + i * 16][nc + 1] = v.y;
            Ls[cl + i * 16][nc + 2] = v.z;
            Ls[cl + i * 16][nc + 3] = v.w;
        }
    }
    __syncthreads();
    int nl = t >> 2, seg = t & 3;       // 16 cin per thread
    bfraw hb[16], lb[16];
#pragma unroll
    for (int j = 0; j < 16; ++j) {
        float v = Ls[seg * 16 + j][nl];
        bfraw h = f2bf(v);
        hb[j] = h;
        lb[j] = f2bf(v - bf2f(h));
    }
    size_t base = ((size_t)b * N_ + n0 + nl) * 256 + c0 + seg * 16;
    *(short8*)&xh[base]     = *(short8*)&hb[0];
    *(short8*)&xh[base + 8] = *(short8*)&hb[8];
    *(short8*)&xl[base]     = *(short8*)&lb[0];
    *(short8*)&xl[base + 8] = *(short8*)&lb[8];
}

// ---------------------------------------------------------------------------
// Kernel 1c: MFMA ygemm.  y = w@x via 3-term bf16 split (wh*xh + wh*xl + wl*xh).
// Block: 64ch x 128n, 4 waves (wave = 32n). ALL fragments direct from global
// (L2-resident).  Stats: in-register shfl reduce -> LDS -> atomics.
// Stores: qkt [b][n][64] (by==0) / d [b][c][n] (by>=1), scalar bf16.
// ---------------------------------------------------------------------------
__global__ __launch_bounds__(256, 2) void ygemm_kernel(uint8_t* __restrict__ wsb)
{
    const bfraw* xh = (const bfraw*)(wsb + XH_OFF_B);
    const bfraw* xl = (const bfraw*)(wsb + XL_OFF_B);
    const bfraw* wh = (const bfraw*)(wsb + WH_OFF_B);
    const bfraw* wl = (const bfraw*)(wsb + WL_OFF_B);
    bfraw* qkt = (bfraw*)wsb;
    bfraw* db  = (bfraw*)(wsb + D_OFF_B);
    float* sums  = (float*)(wsb + SUM_OFF_B);
    float* sumsq = sums + 320;
    __shared__ float redS[4][64], redQ[4][64];

    const int bx = blockIdx.x;           // 0..127 n-tiles of 128
    const int by = blockIdx.y;           // 0..4 ch-tiles of 64
    const int b  = bx >> 5;
    const int n0 = (bx << 7) & (N_ - 1);
    const int t = threadIdx.x, w = t >> 6, l = t & 63, lq = l & 15, lg = l >> 4;
    const int nw = n0 + w * 32;

    float4v acc[4][2];
#pragma unroll
    for (int i = 0; i < 4; ++i)
#pragma unroll
        for (int j = 0; j < 2; ++j) acc[i][j] = (float4v){0.f, 0.f, 0.f, 0.f};

    for (int s = 0; s < 8; ++s) {
        const int k0 = s * 32;
        short8 ah[4], al[4], bh[2], bl[2];
#pragma unroll
        for (int ct = 0; ct < 4; ++ct) {
            size_t off = (size_t)(by * 64 + ct * 16 + lq) * 256 + k0 + lg * 8;
            ah[ct] = *(const short8*)&wh[off];
            al[ct] = *(const short8*)&wl[off];
        }
#pragma unroll
        for (int nt = 0; nt < 2; ++nt) {
            size_t off = ((size_t)b * N_ + nw + nt * 16 + lq) * 256 + k0 + lg * 8;
            bh[nt] = *(const short8*)&xh[off];
            bl[nt] = *(const short8*)&xl[off];
        }
#pragma unroll
        for (int ct = 0; ct < 4; ++ct)
#pragma unroll
            for (int nt = 0; nt < 2; ++nt) {
                acc[ct][nt] = __builtin_amdgcn_mfma_f32_16x16x32_bf16(ah[ct], bh[nt], acc[ct][nt], 0, 0, 0);
                acc[ct][nt] = __builtin_amdgcn_mfma_f32_16x16x32_bf16(al[ct], bh[nt], acc[ct][nt], 0, 0, 0);
                acc[ct][nt] = __builtin_amdgcn_mfma_f32_16x16x32_bf16(ah[ct], bl[nt], acc[ct][nt], 0, 0, 0);
            }
    }
    // ---- stats: reduce over n within wave, stash per-wave partials ----
#pragma unroll
    for (int ct = 0; ct < 4; ++ct) {
        float sv[4], qv[4];
#pragma unroll
        for (int r = 0; r < 4; ++r) {
            float a0 = acc[ct][0][r], a1 = acc[ct][1][r];
            sv[r] = a0 + a1;
            qv[r] = a0 * a0 + a1 * a1;
#pragma unroll
            for (int m = 1; m < 16; m <<= 1) {
                sv[r] += __shfl_xor(sv[r], m);
                qv[r] += __shfl_xor(qv[r], m);
            }
        }
        if (lq == 0) {
#pragma unroll
            for (int r = 0; r < 4; ++r) {
                redS[w][ct * 16 + lg * 4 + r] = sv[r];
                redQ[w][ct * 16 + lg * 4 + r] = qv[r];
            }
        }
    }
    __syncthreads();
    if (t < 64) {
        float s = redS[0][t] + redS[1][t] + redS[2][t] + redS[3][t];
        float q = redQ[0][t] + redQ[1][t] + redQ[2][t] + redQ[3][t];
        atomicAdd(&sums[by * 64 + t], s);
        atomicAdd(&sumsq[by * 64 + t], q);
    }
    // ---- stores ----
    if (by == 0) {
#pragma unroll
        for (int ct = 0; ct < 4; ++ct)
#pragma unroll
            for (int nt = 0; nt < 2; ++nt)
#pragma unroll
                for (int r = 0; r < 4; ++r) {
                    int ch = ct * 16 + lg * 4 + r;
                    int n = nw + nt * 16 + lq;
                    qkt[(((size_t)b * N_ + n) << 6) + ch] = f2bf(acc[ct][nt][r]);
                }
    } else {
#pragma unroll
        for (int ct = 0; ct < 4; ++ct)
#pragma unroll
            for (int nt = 0; nt < 2; ++nt)
#pragma unroll
                for (int r = 0; r < 4; ++r) {
                    int ch = by * 64 - 64 + ct * 16 + lg * 4 + r;
                    int n = nw + nt * 16 + lq;
                    db[((size_t)b * C_ + ch) * N_ + n] = f2bf(acc[ct][nt][r]);
                }
    }
}

// ---------------------------------------------------------------------------
// Kernel 2: finalize BN -> folded scale/bias per channel.
// ---------------------------------------------------------------------------
__global__ void finalize_kernel(
    const float* __restrict__ g1, const float* __restrict__ b1,
    const float* __restrict__ g2, const float* __restrict__ b2,
    const float* __restrict__ g3, const float* __restrict__ b3,
    float* __restrict__ sums)
{
    int ch = threadIdx.x;
    if (ch >= 320) return;
    const float inv = 1.0f / (float)(B_ * N_);
    float mean = sums[ch] * inv;
    float var = sums[320 + ch] * inv - mean * mean;
    float g, bb;
    if (ch < 32)      { g = g1[ch];      bb = b1[ch]; }
    else if (ch < 64) { g = g2[ch - 32]; bb = b2[ch - 32]; }
    else              { g = g3[ch - 64]; bb = b3[ch - 64]; }
    float sc = g * rsqrtf(var + 1e-5f);
    sums[640 + ch] = sc;
    sums[960 + ch] = bb - sc * mean;
}

// ---------------------------------------------------------------------------
// Kernel 3: in-place bf16 relu(sc*y + bi).
// ---------------------------------------------------------------------------
__global__ __launch_bounds__(256) void affine_kernel(uint8_t* __restrict__ wsb)
{
    bfraw* base = (bfraw*)wsb;
    const float* sc = (const float*)(wsb + SUM_OFF_B) + 640;
    const float* bi = sc + 320;
    size_t i8 = ((size_t)blockIdx.x * 256 + threadIdx.x) * 8;
    bfraw4 v0 = *(bfraw4*)&base[i8];
    bfraw4 v1 = *(bfraw4*)&base[i8 + 4];
    if (i8 < QK_BF) {
        int ch0 = (int)(i8 & 63);
        float4 s0 = *(const float4*)&sc[ch0];
        float4 s1 = *(const float4*)&sc[ch0 + 4];
        float4 c0 = *(const float4*)&bi[ch0];
        float4 c1 = *(const float4*)&bi[ch0 + 4];
        float sa[8] = {s0.x, s0.y, s0.z, s0.w, s1.x, s1.y, s1.z, s1.w};
        float ca[8] = {c0.x, c0.y, c0.z, c0.w, c1.x, c1.y, c1.z, c1.w};
#pragma unroll
        for (int j = 0; j < 4; ++j) {
            v0[j] = f2bf(fmaxf(0.f, fmaf(sa[j],     bf2f(v0[j]), ca[j])));
            v1[j] = f2bf(fmaxf(0.f, fmaf(sa[j + 4], bf2f(v1[j]), ca[j + 4])));
        }
    } else {
        int ch = 64 + (int)(((i8 - QK_BF) >> 12) & 255);
        float s = sc[ch], b = bi[ch];
#pragma unroll
        for (int j = 0; j < 4; ++j) {
            v0[j] = f2bf(fmaxf(0.f, fmaf(s, bf2f(v0[j]), b)));
            v1[j] = f2bf(fmaxf(0.f, fmaf(s, bf2f(v1[j]), b)));
        }
    }
    *(bfraw4*)&base[i8] = v0;
    *(bfraw4*)&base[i8 + 4] = v1;
}

// ---------------------------------------------------------------------------
// Kernel 4: softmax stats pass.  ml[b][q] = rowmax + ln(rowsum of exp).
// ---------------------------------------------------------------------------
__global__ __launch_bounds__(256) void mlpass_kernel(uint8_t* __restrict__ wsb)
{
    const bfraw* qkt = (const bfraw*)wsb;
    float* ml = (float*)(wsb + ML_OFF_B);
    const int id = blockIdx.x;
    const int b = id & 3;
    const int n0q = (id >> 2) << 6;
    const int tid = threadIdx.x;
    const int w = tid >> 6, l = tid & 63, lq = l & 15, lg = l >> 4;
    const bfraw* qkb = qkt + ((size_t)b * N_ << 6);
    const short8 qfrag = *(const short8*)&qkb[((size_t)(n0q + w * 16 + lq) << 6) + lg * 8];

    float mx = -1e30f, sum = 0.f;
    for (int n0k = 0; n0k < N_; n0k += 128) {
        float4v st[8];
#pragma unroll
        for (int kt = 0; kt < 8; ++kt) {
            short8 kf = *(const short8*)&qkb[((size_t)(n0k + kt * 16 + lq) << 6) + 32 + lg * 8];
            float4v z = {0.f, 0.f, 0.f, 0.f};
            st[kt] = __builtin_amdgcn_mfma_f32_16x16x32_bf16(kf, qfrag, z, 0, 0, 0);
        }
        float m1 = st[0][0];
#pragma unroll
        for (int kt = 0; kt < 8; ++kt)
#pragma unroll
            for (int r = 0; r < 4; ++r) m1 = fmaxf(m1, st[kt][r]);
        float nm = fmaxf(mx, m1);
        float ae = 0.f;
#pragma unroll
        for (int kt = 0; kt < 8; ++kt)
#pragma unroll
            for (int r = 0; r < 4; ++r) ae += __expf(st[kt][r] - nm);
        sum = sum * __expf(mx - nm) + ae;
        mx = nm;
    }
#pragma unroll
    for (int m = 16; m < 64; m <<= 1) {
        float mo = __shfl_xor(mx, m);
        float so = __shfl_xor(sum, m);
        float nm = fmaxf(mx, mo);
        sum = sum * __expf(mx - nm) + so * __expf(mo - nm);
        mx = nm;
    }
    if (lg == 0) ml[b * N_ + n0q + w * 16 + lq] = mx + __logf(sum);
}

// ---------------------------------------------------------------------------
// Kernel 5: PV flash pass (two-pass; stateless iterations).
// ---------------------------------------------------------------------------
__global__ __launch_bounds__(256, 2) void flash_kernel(
    const float* __restrict__ x, const uint8_t* __restrict__ wsb,
    float* __restrict__ out)
{
    const bfraw* qkt = (const bfraw*)wsb;
    const bfraw* db  = (const bfraw*)(wsb + D_OFF_B);
    const float* ml  = (const float*)(wsb + ML_OFF_B);
    __shared__ bfraw Pl[2][64 * 128];

    const int id  = blockIdx.x;
    const int b   = id & 3;
    const int hf  = (id >> 2) & 1;
    const int n0q = (id >> 3) << 6;
    const int tid = threadIdx.x;
    const int w   = tid >> 6;
    const int l   = tid & 63;
    const int lq  = l & 15;
    const int lg  = l >> 4;
    const int sw  = lq & 7;

    const bfraw* qkb   = qkt + ((size_t)b * N_ << 6);
    const bfraw* dbase = db + ((size_t)b * C_ + hf * 128) * N_;

    const short8 qfrag = *(const short8*)&qkb[((size_t)(n0q + w * 16 + lq) << 6) + lg * 8];
    const float  mlq   = ml[b * N_ + n0q + w * 16 + lq];

    float4v acc[2][4];
#pragma unroll
    for (int i = 0; i < 2; ++i)
#pragma unroll
        for (int j = 0; j < 4; ++j) acc[i][j] = (float4v){0.f, 0.f, 0.f, 0.f};

    short8 kf[8], df[2][4];
#pragma unroll
    for (int kt = 0; kt < 8; ++kt)
        kf[kt] = *(const short8*)&qkb[((size_t)(kt * 16 + lq) << 6) + 32 + lg * 8];
#pragma unroll
    for (int ct = 0; ct < 2; ++ct) {
        int c = (ct * 4 + w) * 16 + lq;
#pragma unroll
        for (int ch = 0; ch < 4; ++ch)
            df[ct][ch] = *(const short8*)&dbase[(size_t)c * N_ + ch * 32 + lg * 8];
    }

    for (int it = 0; it < 32; ++it) {
        const int ib = it & 1;
        const int nk = ((it + 1) & 31) << 7;
        float4v st[8];
#pragma unroll
        for (int kt = 0; kt < 8; ++kt) {
            float4v z = {0.f, 0.f, 0.f, 0.f};
            st[kt] = __builtin_amdgcn_mfma_f32_16x16x32_bf16(kf[kt], qfrag, z, 0, 0, 0);
        }
#pragma unroll
        for (int kt = 0; kt < 8; ++kt)
            kf[kt] = *(const short8*)&qkb[((size_t)(nk + kt * 16 + lq) << 6) + 32 + lg * 8];
#pragma unroll
        for (int kt = 0; kt < 8; ++kt) {
            bfraw4 pk;
#pragma unroll
            for (int r = 0; r < 4; ++r) pk[r] = f2bf(__expf(st[kt][r] - mlq));
            int g = (2 * kt + (lg >> 1)) ^ sw;
            *(bfraw4*)&Pl[ib][(w * 16 + lq) * 128 + g * 8 + (lg & 1) * 4] = pk;
        }
        __syncthreads();
#pragma unroll
        for (int ch = 0; ch < 4; ++ch) {
            short8 bfr[4];
#pragma unroll
            for (int qt = 0; qt < 4; ++qt) {
                int g = (4 * ch + lg) ^ sw;
                bfr[qt] = *(const short8*)&Pl[ib][(qt * 16 + lq) * 128 + g * 8];
            }
#pragma unroll
            for (int ct = 0; ct < 2; ++ct)
#pragma unroll
                for (int qt = 0; qt < 4; ++qt)
                    acc[ct][qt] = __builtin_amdgcn_mfma_f32_16x16x32_bf16(df[ct][ch], bfr[qt], acc[ct][qt], 0, 0, 0);
#pragma unroll
            for (int ct = 0; ct < 2; ++ct) {
                int c = (ct * 4 + w) * 16 + lq;
                df[ct][ch] = *(const short8*)&dbase[(size_t)c * N_ + nk + ch * 32 + lg * 8];
            }
        }
    }
#pragma unroll
    for (int ct = 0; ct < 2; ++ct)
#pragma unroll
        for (int r = 0; r < 4; ++r) {
            int c = hf * 128 + (ct * 4 + w) * 16 + lg * 4 + r;
            size_t base = ((size_t)b * C_ + c) * N_ + n0q;
#pragma unroll
            for (int qt = 0; qt < 4; ++qt) {
                size_t idx = base + qt * 16 + lq;
                out[idx] = x[idx] + acc[ct][qt][r];
            }
        }
}

extern "C" void kernel_launch(void* const* d_in, const int* in_sizes, int n_in,
                              void* d_out, int out_size, void* d_ws, size_t ws_size,
                              hipStream_t stream) {
    (void)in_sizes; (void)n_in; (void)out_size; (void)ws_size;
    const float* x  = (const float*)d_in[0];
    const float* w1 = (const float*)d_in[1];
    const float* w2 = (const float*)d_in[2];
    const float* w3 = (const float*)d_in[3];
    const float* g1 = (const float*)d_in[4];
    const float* b1 = (const float*)d_in[5];
    const float* g2 = (const float*)d_in[6];
    const float* b2 = (const float*)d_in[7];
    const float* g3 = (const float*)d_in[8];
    const float* b3 = (const float*)d_in[9];
    uint8_t* wsb = (uint8_t*)d_ws;
    float* sums = (float*)(wsb + SUM_OFF_B);
    float* outp = (float*)d_out;

    zero_kernel<<<1, 256, 0, stream>>>(sums);
    wsplit_kernel<<<80, 256, 0, stream>>>(w1, w2, w3, wsb);
    xtsplit_kernel<<<1024, 256, 0, stream>>>(x, wsb);
    ygemm_kernel<<<dim3(128, 5), 256, 0, stream>>>(wsb);
    finalize_kernel<<<1, 320, 0, stream>>>(g1, b1, g2, b2, g3, b3, sums);
    affine_kernel<<<(QK_BF + D_BF) / 8 / 256, 256, 0, stream>>>(wsb);
    mlpass_kernel<<<256, 256, 0, stream>>>(wsb);
    flash_kernel<<<N_ / 64 * B_ * 2, 256, 0, stream>>>(x, wsb, outp);
}